// Round 1
// baseline (165.490 us; speedup 1.0000x reference)
//
#include <hip/hip_runtime.h>

#define DD 16
#define EPS 1e-5f
#define BLOCK 256

__global__ __launch_bounds__(BLOCK) void twoln_kernel(
    const float* __restrict__ x,
    const float* __restrict__ ln1w_g, const float* __restrict__ ln1b_g,
    const float* __restrict__ fcw_g,  const float* __restrict__ fcb_g,
    const float* __restrict__ ln2w_g, const float* __restrict__ ln2b_g,
    const float* __restrict__ mask,
    float* __restrict__ out, int n)
{
    __shared__ float sw[DD * DD];
    __shared__ float sfcb[DD], s1w[DD], s1b[DD], s2w[DD], s2b[DD];

    const int t = threadIdx.x;
    if (t < DD * DD) sw[t] = fcw_g[t];
    if (t < DD) {
        sfcb[t] = fcb_g[t];
        s1w[t] = ln1w_g[t]; s1b[t] = ln1b_g[t];
        s2w[t] = ln2w_g[t]; s2b[t] = ln2b_g[t];
    }
    __syncthreads();

    const long long row = (long long)blockIdx.x * BLOCK + t;
    if (row >= n) return;

    const float4* xp = reinterpret_cast<const float4*>(x + row * DD);
    float4 xv0 = xp[0], xv1 = xp[1], xv2 = xp[2], xv3 = xp[3];

    float xs[DD];
    *reinterpret_cast<float4*>(&xs[0])  = xv0;
    *reinterpret_cast<float4*>(&xs[4])  = xv1;
    *reinterpret_cast<float4*>(&xs[8])  = xv2;
    *reinterpret_cast<float4*>(&xs[12]) = xv3;

    // ---- LN1 ----
    float s = 0.f;
#pragma unroll
    for (int k = 0; k < DD; ++k) s += xs[k];
    const float mu1 = s * (1.0f / DD);
    float v = 0.f;
#pragma unroll
    for (int k = 0; k < DD; ++k) { float d = xs[k] - mu1; v += d * d; }
    const float rs1 = rsqrtf(v * (1.0f / DD) + EPS);

    float h[DD];
#pragma unroll
    for (int k = 0; k < DD; ++k)
        h[k] = (xs[k] - mu1) * rs1 * s1w[k] + s1b[k];

    // ---- mask load (overlap with matmul below via scheduler) ----
    const float4* mp = reinterpret_cast<const float4*>(mask + row * DD);
    float4 mv0 = mp[0], mv1 = mp[1], mv2 = mp[2], mv3 = mp[3];
    float mk[DD];
    *reinterpret_cast<float4*>(&mk[0])  = mv0;
    *reinterpret_cast<float4*>(&mk[4])  = mv1;
    *reinterpret_cast<float4*>(&mk[8])  = mv2;
    *reinterpret_cast<float4*>(&mk[12]) = mv3;

    // ---- Linear: g[j] = dot(h, W[j,:]) + b[j]; then dropout-mask mul + ReLU ----
    float g[DD];
#pragma unroll
    for (int j = 0; j < DD; ++j) {
        float acc = sfcb[j];
#pragma unroll
        for (int k = 0; k < DD; ++k)
            acc = fmaf(h[k], sw[j * DD + k], acc);
        g[j] = fmaxf(acc * mk[j], 0.0f);
    }

    // ---- LN2 ----
    float s2 = 0.f;
#pragma unroll
    for (int k = 0; k < DD; ++k) s2 += g[k];
    const float mu2 = s2 * (1.0f / DD);
    float v2 = 0.f;
#pragma unroll
    for (int k = 0; k < DD; ++k) { float d = g[k] - mu2; v2 += d * d; }
    const float rs2 = rsqrtf(v2 * (1.0f / DD) + EPS);

    float o[DD];
#pragma unroll
    for (int k = 0; k < DD; ++k)
        o[k] = (g[k] - mu2) * rs2 * s2w[k] + s2b[k];

    float4* op = reinterpret_cast<float4*>(out + row * DD);
    op[0] = *reinterpret_cast<const float4*>(&o[0]);
    op[1] = *reinterpret_cast<const float4*>(&o[4]);
    op[2] = *reinterpret_cast<const float4*>(&o[8]);
    op[3] = *reinterpret_cast<const float4*>(&o[12]);
}

extern "C" void kernel_launch(void* const* d_in, const int* in_sizes, int n_in,
                              void* d_out, int out_size, void* d_ws, size_t ws_size,
                              hipStream_t stream)
{
    const float* x     = (const float*)d_in[0];
    const float* ln1w  = (const float*)d_in[1];
    const float* ln1b  = (const float*)d_in[2];
    const float* fcw   = (const float*)d_in[3];
    const float* fcb   = (const float*)d_in[4];
    const float* ln2w  = (const float*)d_in[5];
    const float* ln2b  = (const float*)d_in[6];
    const float* mask  = (const float*)d_in[7];
    float* out = (float*)d_out;

    const int n = in_sizes[0] / DD;  // number of rows
    const int grid = (n + BLOCK - 1) / BLOCK;
    twoln_kernel<<<grid, BLOCK, 0, stream>>>(x, ln1w, ln1b, fcw, fcb,
                                             ln2w, ln2b, mask, out, n);
}

// Round 2
// 156.868 us; speedup vs baseline: 1.0550x; 1.0550x over previous
//
#include <hip/hip_runtime.h>

#define DD 16
#define EPS 1e-5f
#define BLOCK 256

__global__ __launch_bounds__(BLOCK) void twoln_kernel(
    const float* __restrict__ x,
    const float* __restrict__ ln1w, const float* __restrict__ ln1b,
    const float* __restrict__ fcw,  const float* __restrict__ fcb,
    const float* __restrict__ ln2w, const float* __restrict__ ln2b,
    const float* __restrict__ mask,
    float* __restrict__ out, int n)
{
    const long long row = (long long)blockIdx.x * BLOCK + threadIdx.x;
    if (row >= n) return;

    // ---- issue both row loads up front (independent, hide latency) ----
    const float4* xp = reinterpret_cast<const float4*>(x + row * DD);
    const float4* mp = reinterpret_cast<const float4*>(mask + row * DD);
    float4 xv0 = xp[0], xv1 = xp[1], xv2 = xp[2], xv3 = xp[3];
    float4 mv0 = mp[0], mv1 = mp[1], mv2 = mp[2], mv3 = mp[3];

    float xs[DD];
    *reinterpret_cast<float4*>(&xs[0])  = xv0;
    *reinterpret_cast<float4*>(&xs[4])  = xv1;
    *reinterpret_cast<float4*>(&xs[8])  = xv2;
    *reinterpret_cast<float4*>(&xs[12]) = xv3;

    // ---- LN1 (weights via uniform/scalar loads) ----
    float s = 0.f;
#pragma unroll
    for (int k = 0; k < DD; ++k) s += xs[k];
    const float mu1 = s * (1.0f / DD);
    float v = 0.f;
#pragma unroll
    for (int k = 0; k < DD; ++k) { float d = xs[k] - mu1; v += d * d; }
    const float rs1 = rsqrtf(v * (1.0f / DD) + EPS);

    float h[DD];
#pragma unroll
    for (int k = 0; k < DD; ++k)
        h[k] = (xs[k] - mu1) * rs1 * ln1w[k] + ln1b[k];

    float mk[DD];
    *reinterpret_cast<float4*>(&mk[0])  = mv0;
    *reinterpret_cast<float4*>(&mk[4])  = mv1;
    *reinterpret_cast<float4*>(&mk[8])  = mv2;
    *reinterpret_cast<float4*>(&mk[12]) = mv3;

    // ---- Linear: W rows read with wave-uniform compile-time indices
    //      -> s_load_dwordx16 into SGPRs, inner loop is v_fmac v,s,v ----
    float g[DD];
#pragma unroll
    for (int j = 0; j < DD; ++j) {
        float acc = fcb[j];
#pragma unroll
        for (int k = 0; k < DD; ++k)
            acc = fmaf(h[k], fcw[j * DD + k], acc);
        g[j] = fmaxf(acc * mk[j], 0.0f);
    }

    // ---- LN2 ----
    float s2 = 0.f;
#pragma unroll
    for (int k = 0; k < DD; ++k) s2 += g[k];
    const float mu2 = s2 * (1.0f / DD);
    float v2 = 0.f;
#pragma unroll
    for (int k = 0; k < DD; ++k) { float d = g[k] - mu2; v2 += d * d; }
    const float rs2 = rsqrtf(v2 * (1.0f / DD) + EPS);

    float o[DD];
#pragma unroll
    for (int k = 0; k < DD; ++k)
        o[k] = (g[k] - mu2) * rs2 * ln2w[k] + ln2b[k];

    float4* op = reinterpret_cast<float4*>(out + row * DD);
    op[0] = *reinterpret_cast<const float4*>(&o[0]);
    op[1] = *reinterpret_cast<const float4*>(&o[4]);
    op[2] = *reinterpret_cast<const float4*>(&o[8]);
    op[3] = *reinterpret_cast<const float4*>(&o[12]);
}

extern "C" void kernel_launch(void* const* d_in, const int* in_sizes, int n_in,
                              void* d_out, int out_size, void* d_ws, size_t ws_size,
                              hipStream_t stream)
{
    const float* x     = (const float*)d_in[0];
    const float* ln1w  = (const float*)d_in[1];
    const float* ln1b  = (const float*)d_in[2];
    const float* fcw   = (const float*)d_in[3];
    const float* fcb   = (const float*)d_in[4];
    const float* ln2w  = (const float*)d_in[5];
    const float* ln2b  = (const float*)d_in[6];
    const float* mask  = (const float*)d_in[7];
    float* out = (float*)d_out;

    const int n = in_sizes[0] / DD;  // number of rows
    const int grid = (n + BLOCK - 1) / BLOCK;
    twoln_kernel<<<grid, BLOCK, 0, stream>>>(x, ln1w, ln1b, fcw, fcb,
                                             ln2w, ln2b, mask, out, n);
}

// Round 4
// 151.759 us; speedup vs baseline: 1.0905x; 1.0337x over previous
//
#include <hip/hip_runtime.h>

#define DD 16
#define EPS 1e-5f
#define BLOCK 256
#define GRID 1024   // 1024 blocks x 4 waves = 4096 waves; 262144 groups -> 64 iters/wave

typedef float floatx4 __attribute__((ext_vector_type(4)));

// Quad-cooperative: 4 lanes per row. Lane layout within a wave:
//   lane = 4*rsub + p ; rsub = row-within-group (0..15), p = part (0..3)
//   lane's float4 = elements [4p .. 4p+3] of row (group*16 + rsub)
// Global loads/stores: flat float4 index = group*64 + lane  -> fully coalesced 1KB/instr.
__global__ __launch_bounds__(BLOCK) void twoln_kernel(
    const float* __restrict__ x,
    const float* __restrict__ ln1w, const float* __restrict__ ln1b,
    const float* __restrict__ fcw,  const float* __restrict__ fcb,
    const float* __restrict__ ln2w, const float* __restrict__ ln2b,
    const float* __restrict__ mask,
    float* __restrict__ out, long long nrows)
{
    const int lane = threadIdx.x & 63;
    const int p    = lane & 3;      // which 4-element part of the row this lane owns
    const int rsub = lane >> 2;     // row within the 16-row group

    // ---- per-lane parameters (loaded once, amortized over the grid-stride loop) ----
    float l1w[4], l1b[4], l2w[4], l2b[4], fb[4];
#pragma unroll
    for (int kk = 0; kk < 4; ++kk) {
        l1w[kk] = ln1w[4 * p + kk];
        l1b[kk] = ln1b[4 * p + kk];
        l2w[kk] = ln2w[4 * p + kk];
        l2b[kk] = ln2b[4 * p + kk];
    }
#pragma unroll
    for (int jj = 0; jj < 4; ++jj) fb[jj] = fcb[4 * p + jj];

    // W in VGPRs: this lane computes outputs j = 4p+jj. It will receive h in
    // chunk order c = [self, ^1, ^2, ^3] = parts [p, p^1, p^2, p^3], so store
    // W pre-permuted to match: Wreg[jj][c][kk] = fcw[(4p+jj)*16 + 4*(p^c) + kk].
    // All loop indices below are compile-time -> registers, no scratch.
    float Wreg[4][4][4];
#pragma unroll
    for (int jj = 0; jj < 4; ++jj) {
#pragma unroll
        for (int c = 0; c < 4; ++c) {
            const float4 wv = *reinterpret_cast<const float4*>(
                fcw + (4 * p + jj) * DD + 4 * (p ^ c));
            Wreg[jj][c][0] = wv.x; Wreg[jj][c][1] = wv.y;
            Wreg[jj][c][2] = wv.z; Wreg[jj][c][3] = wv.w;
        }
    }

    const long long ngroups = (nrows + 15) >> 4;
    const long long gw0 = (long long)blockIdx.x * (BLOCK / 64) + (threadIdx.x >> 6);
    const long long nw  = (long long)gridDim.x * (BLOCK / 64);

    const float4* __restrict__ xf = reinterpret_cast<const float4*>(x);
    const float4* __restrict__ mf = reinterpret_cast<const float4*>(mask);
    floatx4* __restrict__ of = reinterpret_cast<floatx4*>(out);

    for (long long g = gw0; g < ngroups; g += nw) {
        const long long row = g * 16 + rsub;
        const bool act = row < nrows;
        const long long idx = g * 64 + lane;

        float4 xv = act ? xf[idx] : make_float4(0.f, 0.f, 0.f, 0.f);
        float4 mv = act ? mf[idx] : make_float4(0.f, 0.f, 0.f, 0.f);

        // ---- LN1: quad reduction (lanes 4r..4r+3 share a row) ----
        float sl = xv.x + xv.y + xv.z + xv.w;
        sl += __shfl_xor(sl, 1);
        sl += __shfl_xor(sl, 2);
        const float mu1 = sl * (1.0f / DD);

        const float e0 = xv.x - mu1, e1 = xv.y - mu1, e2 = xv.z - mu1, e3 = xv.w - mu1;
        float vl = e0 * e0 + e1 * e1 + e2 * e2 + e3 * e3;
        vl += __shfl_xor(vl, 1);
        vl += __shfl_xor(vl, 2);
        const float rs1 = rsqrtf(vl * (1.0f / DD) + EPS);

        float h[4];
        h[0] = e0 * rs1 * l1w[0] + l1b[0];
        h[1] = e1 * rs1 * l1w[1] + l1b[1];
        h[2] = e2 * rs1 * l1w[2] + l1b[2];
        h[3] = e3 * rs1 * l1w[3] + l1b[3];

        // ---- all-gather h within the quad: ch[c][kk] = h of lane^c ----
        float ch[4][4];
#pragma unroll
        for (int kk = 0; kk < 4; ++kk) ch[0][kk] = h[kk];
#pragma unroll
        for (int kk = 0; kk < 4; ++kk) ch[1][kk] = __shfl_xor(h[kk], 1);
#pragma unroll
        for (int kk = 0; kk < 4; ++kk) ch[2][kk] = __shfl_xor(h[kk], 2);
#pragma unroll
        for (int kk = 0; kk < 4; ++kk) ch[3][kk] = __shfl_xor(ch[1][kk], 2);

        // ---- Linear (j = 4p+jj) + dropout-mask + ReLU ----
        float gv[4];
#pragma unroll
        for (int jj = 0; jj < 4; ++jj) {
            float acc = fb[jj];
#pragma unroll
            for (int c = 0; c < 4; ++c)
#pragma unroll
                for (int kk = 0; kk < 4; ++kk)
                    acc = fmaf(ch[c][kk], Wreg[jj][c][kk], acc);
            gv[jj] = acc;
        }
        gv[0] = fmaxf(gv[0] * mv.x, 0.f);
        gv[1] = fmaxf(gv[1] * mv.y, 0.f);
        gv[2] = fmaxf(gv[2] * mv.z, 0.f);
        gv[3] = fmaxf(gv[3] * mv.w, 0.f);

        // ---- LN2: quad reduction again ----
        float s2 = gv[0] + gv[1] + gv[2] + gv[3];
        s2 += __shfl_xor(s2, 1);
        s2 += __shfl_xor(s2, 2);
        const float mu2 = s2 * (1.0f / DD);

        const float d0 = gv[0] - mu2, d1 = gv[1] - mu2, d2 = gv[2] - mu2, d3 = gv[3] - mu2;
        float v2 = d0 * d0 + d1 * d1 + d2 * d2 + d3 * d3;
        v2 += __shfl_xor(v2, 1);
        v2 += __shfl_xor(v2, 2);
        const float rs2 = rsqrtf(v2 * (1.0f / DD) + EPS);

        floatx4 ov;
        ov.x = d0 * rs2 * l2w[0] + l2b[0];
        ov.y = d1 * rs2 * l2w[1] + l2b[1];
        ov.z = d2 * rs2 * l2w[2] + l2b[2];
        ov.w = d3 * rs2 * l2w[3] + l2b[3];

        if (act) __builtin_nontemporal_store(ov, &of[idx]);
    }
}

extern "C" void kernel_launch(void* const* d_in, const int* in_sizes, int n_in,
                              void* d_out, int out_size, void* d_ws, size_t ws_size,
                              hipStream_t stream)
{
    const float* x     = (const float*)d_in[0];
    const float* ln1w  = (const float*)d_in[1];
    const float* ln1b  = (const float*)d_in[2];
    const float* fcw   = (const float*)d_in[3];
    const float* fcb   = (const float*)d_in[4];
    const float* ln2w  = (const float*)d_in[5];
    const float* ln2b  = (const float*)d_in[6];
    const float* mask  = (const float*)d_in[7];
    float* out = (float*)d_out;

    const long long nrows = (long long)in_sizes[0] / DD;
    twoln_kernel<<<GRID, BLOCK, 0, stream>>>(x, ln1w, ln1b, fcw, fcb,
                                             ln2w, ln2b, mask, out, nrows);
}

// Round 5
// 122.210 us; speedup vs baseline: 1.3541x; 1.2418x over previous
//
#include <hip/hip_runtime.h>

#define DD 16
#define EPS 1e-5f
#define BLOCK 256
#define GRID 2048   // 2048 blocks x 4 waves = 8192 waves = 100% of wave slots

typedef float floatx4 __attribute__((ext_vector_type(4)));

// Quad-cooperative: 4 lanes per row. lane = 4*rsub + p; lane owns elements
// [4p..4p+3] of row (group*16 + rsub). Flat float4 idx = g*64 + lane -> 1KB
// contiguous per wave VMEM instruction.
template<bool EXACT>
__global__ __launch_bounds__(BLOCK) void twoln_kernel(
    const float* __restrict__ x,
    const float* __restrict__ ln1w, const float* __restrict__ ln1b,
    const float* __restrict__ fcw,  const float* __restrict__ fcb,
    const float* __restrict__ ln2w, const float* __restrict__ ln2b,
    const float* __restrict__ mask,
    float* __restrict__ out, long long nrows)
{
    const int lane = threadIdx.x & 63;
    const int p    = lane & 3;
    const int rsub = lane >> 2;

    float l1w[4], l1b[4], l2w[4], l2b[4], fb[4];
#pragma unroll
    for (int kk = 0; kk < 4; ++kk) {
        l1w[kk] = ln1w[4 * p + kk];
        l1b[kk] = ln1b[4 * p + kk];
        l2w[kk] = ln2w[4 * p + kk];
        l2b[kk] = ln2b[4 * p + kk];
    }
#pragma unroll
    for (int jj = 0; jj < 4; ++jj) fb[jj] = fcb[4 * p + jj];

    // Wreg[jj][c][kk] = fcw[(4p+jj)*16 + 4*(p^c) + kk] (pre-permuted to the
    // quad shuffle chunk order; all indices compile-time).
    float Wreg[4][4][4];
#pragma unroll
    for (int jj = 0; jj < 4; ++jj) {
#pragma unroll
        for (int c = 0; c < 4; ++c) {
            const float4 wv = *reinterpret_cast<const float4*>(
                fcw + (4 * p + jj) * DD + 4 * (p ^ c));
            Wreg[jj][c][0] = wv.x; Wreg[jj][c][1] = wv.y;
            Wreg[jj][c][2] = wv.z; Wreg[jj][c][3] = wv.w;
        }
    }

    const long long ngroups = (nrows + 15) >> 4;
    const long long gw0 = (long long)blockIdx.x * (BLOCK / 64) + (threadIdx.x >> 6);
    const long long nw  = (long long)gridDim.x * (BLOCK / 64);

    const floatx4* __restrict__ xf = reinterpret_cast<const floatx4*>(x);
    const floatx4* __restrict__ mf = reinterpret_cast<const floatx4*>(mask);
    floatx4* __restrict__ of = reinterpret_cast<floatx4*>(out);

    if (EXACT) {
        // nrows%16==0 and ngroups%nw==0: no guards, clean 1-deep prefetch.
        if (gw0 >= ngroups) return;
        floatx4 xv_n = xf[gw0 * 64 + lane];
        floatx4 mv_n = __builtin_nontemporal_load(&mf[gw0 * 64 + lane]);

        for (long long g = gw0; g < ngroups; g += nw) {
            const floatx4 xv = xv_n;
            const floatx4 mv = mv_n;
            const long long gn = g + nw;
            if (gn < ngroups) {                       // wave-uniform branch
                xv_n = xf[gn * 64 + lane];
                mv_n = __builtin_nontemporal_load(&mf[gn * 64 + lane]);
            }

            // ---- LN1 ----
            float sl = xv[0] + xv[1] + xv[2] + xv[3];
            sl += __shfl_xor(sl, 1);
            sl += __shfl_xor(sl, 2);
            const float mu1 = sl * (1.0f / DD);
            const float e0 = xv[0] - mu1, e1 = xv[1] - mu1,
                        e2 = xv[2] - mu1, e3 = xv[3] - mu1;
            float vl = e0 * e0 + e1 * e1 + e2 * e2 + e3 * e3;
            vl += __shfl_xor(vl, 1);
            vl += __shfl_xor(vl, 2);
            const float rs1 = rsqrtf(vl * (1.0f / DD) + EPS);

            float h[4];
            h[0] = e0 * rs1 * l1w[0] + l1b[0];
            h[1] = e1 * rs1 * l1w[1] + l1b[1];
            h[2] = e2 * rs1 * l1w[2] + l1b[2];
            h[3] = e3 * rs1 * l1w[3] + l1b[3];

            // ---- quad all-gather of h ----
            float ch[4][4];
#pragma unroll
            for (int kk = 0; kk < 4; ++kk) ch[0][kk] = h[kk];
#pragma unroll
            for (int kk = 0; kk < 4; ++kk) ch[1][kk] = __shfl_xor(h[kk], 1);
#pragma unroll
            for (int kk = 0; kk < 4; ++kk) ch[2][kk] = __shfl_xor(h[kk], 2);
#pragma unroll
            for (int kk = 0; kk < 4; ++kk) ch[3][kk] = __shfl_xor(ch[1][kk], 2);

            // ---- Linear + mask + ReLU ----
            float gv[4];
#pragma unroll
            for (int jj = 0; jj < 4; ++jj) {
                float acc = fb[jj];
#pragma unroll
                for (int c = 0; c < 4; ++c)
#pragma unroll
                    for (int kk = 0; kk < 4; ++kk)
                        acc = fmaf(ch[c][kk], Wreg[jj][c][kk], acc);
                gv[jj] = acc;
            }
            gv[0] = fmaxf(gv[0] * mv[0], 0.f);
            gv[1] = fmaxf(gv[1] * mv[1], 0.f);
            gv[2] = fmaxf(gv[2] * mv[2], 0.f);
            gv[3] = fmaxf(gv[3] * mv[3], 0.f);

            // ---- LN2 ----
            float s2 = gv[0] + gv[1] + gv[2] + gv[3];
            s2 += __shfl_xor(s2, 1);
            s2 += __shfl_xor(s2, 2);
            const float mu2 = s2 * (1.0f / DD);
            const float d0 = gv[0] - mu2, d1 = gv[1] - mu2,
                        d2 = gv[2] - mu2, d3 = gv[3] - mu2;
            float v2 = d0 * d0 + d1 * d1 + d2 * d2 + d3 * d3;
            v2 += __shfl_xor(v2, 1);
            v2 += __shfl_xor(v2, 2);
            const float rs2 = rsqrtf(v2 * (1.0f / DD) + EPS);

            floatx4 ov;
            ov[0] = d0 * rs2 * l2w[0] + l2b[0];
            ov[1] = d1 * rs2 * l2w[1] + l2b[1];
            ov[2] = d2 * rs2 * l2w[2] + l2b[2];
            ov[3] = d3 * rs2 * l2w[3] + l2b[3];

            __builtin_nontemporal_store(ov, &of[g * 64 + lane]);
        }
    } else {
        // General guarded path (tail-safe), no prefetch.
        for (long long g = gw0; g < ngroups; g += nw) {
            const long long row = g * 16 + rsub;
            const bool act = row < nrows;
            const long long idx = g * 64 + lane;
            floatx4 xv = {0.f, 0.f, 0.f, 0.f}, mv = {0.f, 0.f, 0.f, 0.f};
            if (act) { xv = xf[idx]; mv = mf[idx]; }

            float sl = xv[0] + xv[1] + xv[2] + xv[3];
            sl += __shfl_xor(sl, 1);
            sl += __shfl_xor(sl, 2);
            const float mu1 = sl * (1.0f / DD);
            const float e0 = xv[0] - mu1, e1 = xv[1] - mu1,
                        e2 = xv[2] - mu1, e3 = xv[3] - mu1;
            float vl = e0 * e0 + e1 * e1 + e2 * e2 + e3 * e3;
            vl += __shfl_xor(vl, 1);
            vl += __shfl_xor(vl, 2);
            const float rs1 = rsqrtf(vl * (1.0f / DD) + EPS);

            float h[4];
            h[0] = e0 * rs1 * l1w[0] + l1b[0];
            h[1] = e1 * rs1 * l1w[1] + l1b[1];
            h[2] = e2 * rs1 * l1w[2] + l1b[2];
            h[3] = e3 * rs1 * l1w[3] + l1b[3];

            float ch[4][4];
#pragma unroll
            for (int kk = 0; kk < 4; ++kk) ch[0][kk] = h[kk];
#pragma unroll
            for (int kk = 0; kk < 4; ++kk) ch[1][kk] = __shfl_xor(h[kk], 1);
#pragma unroll
            for (int kk = 0; kk < 4; ++kk) ch[2][kk] = __shfl_xor(h[kk], 2);
#pragma unroll
            for (int kk = 0; kk < 4; ++kk) ch[3][kk] = __shfl_xor(ch[1][kk], 2);

            float gv[4];
#pragma unroll
            for (int jj = 0; jj < 4; ++jj) {
                float acc = fb[jj];
#pragma unroll
                for (int c = 0; c < 4; ++c)
#pragma unroll
                    for (int kk = 0; kk < 4; ++kk)
                        acc = fmaf(ch[c][kk], Wreg[jj][c][kk], acc);
                gv[jj] = acc;
            }
            gv[0] = fmaxf(gv[0] * mv[0], 0.f);
            gv[1] = fmaxf(gv[1] * mv[1], 0.f);
            gv[2] = fmaxf(gv[2] * mv[2], 0.f);
            gv[3] = fmaxf(gv[3] * mv[3], 0.f);

            float s2 = gv[0] + gv[1] + gv[2] + gv[3];
            s2 += __shfl_xor(s2, 1);
            s2 += __shfl_xor(s2, 2);
            const float mu2 = s2 * (1.0f / DD);
            const float d0 = gv[0] - mu2, d1 = gv[1] - mu2,
                        d2 = gv[2] - mu2, d3 = gv[3] - mu2;
            float v2 = d0 * d0 + d1 * d1 + d2 * d2 + d3 * d3;
            v2 += __shfl_xor(v2, 1);
            v2 += __shfl_xor(v2, 2);
            const float rs2 = rsqrtf(v2 * (1.0f / DD) + EPS);

            floatx4 ov;
            ov[0] = d0 * rs2 * l2w[0] + l2b[0];
            ov[1] = d1 * rs2 * l2w[1] + l2b[1];
            ov[2] = d2 * rs2 * l2w[2] + l2b[2];
            ov[3] = d3 * rs2 * l2w[3] + l2b[3];

            if (act) __builtin_nontemporal_store(ov, &of[idx]);
        }
    }
}

extern "C" void kernel_launch(void* const* d_in, const int* in_sizes, int n_in,
                              void* d_out, int out_size, void* d_ws, size_t ws_size,
                              hipStream_t stream)
{
    const float* x     = (const float*)d_in[0];
    const float* ln1w  = (const float*)d_in[1];
    const float* ln1b  = (const float*)d_in[2];
    const float* fcw   = (const float*)d_in[3];
    const float* fcb   = (const float*)d_in[4];
    const float* ln2w  = (const float*)d_in[5];
    const float* ln2b  = (const float*)d_in[6];
    const float* mask  = (const float*)d_in[7];
    float* out = (float*)d_out;

    const long long nrows = (long long)in_sizes[0] / DD;
    const long long ngroups = (nrows + 15) >> 4;
    const long long nw = (long long)GRID * (BLOCK / 64);
    const bool exact = (nrows % 16 == 0) && (ngroups % nw == 0);

    if (exact)
        twoln_kernel<true><<<GRID, BLOCK, 0, stream>>>(
            x, ln1w, ln1b, fcw, fcb, ln2w, ln2b, mask, out, nrows);
    else
        twoln_kernel<false><<<GRID, BLOCK, 0, stream>>>(
            x, ln1w, ln1b, fcw, fcb, ln2w, ln2b, mask, out, nrows);
}